// Round 15
// baseline (364.439 us; speedup 1.0000x reference)
//
#include <hip/hip_runtime.h>

// PWC-Net cost volume, fp32. B=4, C=128, H=256, W=448, 81 shifts.
// out[b, di*9+dj, h, w] = (1/128) * sum_c feat1[b,c,h,w] * feat2[b,c,h+di-4,w+dj-4]
//
// All-global, zero-DS design. One wave per (b,h,di,half): 18432 waves. Lane
// owns 4 px (G = half*56 + lane, 56 active). The 12-float window for 9 dj is
// exactly 3 ALIGNED quads: G-1 | G | G+1. Per channel, 4 b128 loads per lane
// (1 feat1 + 3 feat2), every one dense-coalesced (16B lane stride). No
// ds_bpermute, no LDS, no barriers -> DS pipe idle; VALU ~76cy/iter; the
// kernel becomes L1-line-rate bound (~56 line-cy/wave-iter).
// Edge quads clamped in-bounds; garbage reaches only acc slots whose outputs
// are defined 0 (masked at store). OOB rows wave-uniform: store zeros, exit.
// Distance-2 prefetch, 3 rotating sets, period-3 unroll (no reg moves).

typedef __attribute__((ext_vector_type(4))) float f32x4;

__global__ __launch_bounds__(256, 4) void cv_kernel(
    const float* __restrict__ feat1,
    const float* __restrict__ feat2,
    float* __restrict__ out)
{
    constexpr int C = 128, H = 256, W = 448;
    constexpr unsigned HW = (unsigned)(H * W);

    const int tid  = threadIdx.x;
    const int wid  = tid >> 6;
    const int lane = tid & 63;

    // 4608 blocks = 8 * 576: XCD-contiguous item mapping (bijective).
    const int swz   = (blockIdx.x & 7) * 576 + (blockIdx.x >> 3);
    const int item2 = swz * 4 + wid;          // 0..18431
    const int half  = item2 & 1;
    const int item  = item2 >> 1;             // 0..9215
    const int di    = item % 9;
    const int bh    = item / 9;
    const int h     = bh & 255;
    const int b     = bh >> 8;

    const int mg = (lane < 56) ? lane : 55;   // local group 0..55
    const int G  = half * 56 + mg;            // global group 0..111
    const int hr = h + di - 4;

    float* ob = out + (((size_t)(b * 81 + di * 9)) * H + h) * W + G * 4;

    if (hr < 0 || hr >= H) {                  // wave-uniform: whole row zero
        if (lane < 56) {
            const f32x4 z = {0.f, 0.f, 0.f, 0.f};
#pragma unroll
            for (int dj = 0; dj < 9; ++dj)
                *(f32x4*)(ob + (size_t)dj * HW) = z;
        }
        return;
    }

    // Quad pointers (float offsets), edge-clamped in-bounds.
    const unsigned base1 = (unsigned)(((b * C * H) + h) * W);
    const unsigned base2 = (unsigned)(((b * C * H) + hr) * W);
    unsigned f1o  = base1 + (unsigned)(G * 4);
    unsigned f2oL = base2 + (unsigned)((G == 0)   ? 0       : (G - 1) * 4);
    unsigned f2oC = base2 + (unsigned)(G * 4);
    unsigned f2oR = base2 + (unsigned)((G == 111) ? 111 * 4 : (G + 1) * 4);

    float acc[9][4];
#pragma unroll
    for (int j = 0; j < 9; ++j)
#pragma unroll
        for (int p = 0; p < 4; ++p) acc[j][p] = 0.0f;

    // 3 rotating load sets (A=f1, L/Cq/R=f2 quads); distance-2 prefetch.
    f32x4 xA, xL, xC, xR, yA, yL, yC, yR, zA, zL, zC, zR;

#define LOADSET(A, L, Cq, R) do { \
    A  = *(const f32x4*)(feat1 + f1o); \
    L  = *(const f32x4*)(feat2 + f2oL); \
    Cq = *(const f32x4*)(feat2 + f2oC); \
    R  = *(const f32x4*)(feat2 + f2oR); \
    f1o += HW; f2oL += HW; f2oC += HW; f2oR += HW; } while (0)

#define COMPSET(A, L, Cq, R) do { \
    const float w[12] = {L.x, L.y, L.z, L.w, Cq.x, Cq.y, Cq.z, Cq.w, \
                         R.x, R.y, R.z, R.w}; \
    const float a[4] = {A.x, A.y, A.z, A.w}; \
    _Pragma("unroll") \
    for (int dj = 0; dj < 9; ++dj) { \
        _Pragma("unroll") \
        for (int p = 0; p < 4; ++p) \
            acc[dj][p] = fmaf(a[p], w[dj + p], acc[dj][p]); \
    } } while (0)

    LOADSET(xA, xL, xC, xR);                  // ch 0
    LOADSET(yA, yL, yC, yR);                  // ch 1

    for (int g = 0; g < 42; ++g) {            // channels 3g .. 3g+2
        LOADSET(zA, zL, zC, zR);              // ch 3g+2
        COMPSET(xA, xL, xC, xR);              // ch 3g
        LOADSET(xA, xL, xC, xR);              // ch 3g+3
        COMPSET(yA, yL, yC, yR);              // ch 3g+1
        LOADSET(yA, yL, yC, yR);              // ch 3g+4
        COMPSET(zA, zL, zC, zR);              // ch 3g+2
    }
    COMPSET(xA, xL, xC, xR);                  // ch 126
    COMPSET(yA, yL, yC, yR);                  // ch 127

#undef LOADSET
#undef COMPSET

    if (lane < 56) {
        const float s = 1.0f / 128.0f;
        const bool leftEdge  = (G == 0);
        const bool rightEdge = (G == 111);
#pragma unroll
        for (int dj = 0; dj < 9; ++dj) {
            float o[4];
#pragma unroll
            for (int p = 0; p < 4; ++p) {
                float v = acc[dj][p] * s;
                // out col = 4G + p + dj - 4: left-quad garbage -> dj+p<4,
                // right-quad garbage -> dj+p>7.
                if (dj + p < 4) v = leftEdge  ? 0.f : v;
                if (dj + p > 7) v = rightEdge ? 0.f : v;
                o[p] = v;
            }
            f32x4 ov = {o[0], o[1], o[2], o[3]};
            *(f32x4*)(ob + (size_t)dj * HW) = ov;
        }
    }
}

extern "C" void kernel_launch(void* const* d_in, const int* in_sizes, int n_in,
                              void* d_out, int out_size, void* d_ws, size_t ws_size,
                              hipStream_t stream) {
    const float* feat1 = (const float*)d_in[0];
    const float* feat2 = (const float*)d_in[1];
    float* out = (float*)d_out;
    cv_kernel<<<dim3(4608), dim3(256), 0, stream>>>(feat1, feat2, out);
}